// Round 11
// baseline (199.552 us; speedup 1.0000x reference)
//
#include <hip/hip_runtime.h>
#include <math.h>

typedef __attribute__((ext_vector_type(8))) short bf16x8;
typedef __attribute__((ext_vector_type(4))) float f32x4;

__device__ __forceinline__ unsigned short f2bf(float f) {
    unsigned u = __builtin_bit_cast(unsigned, f);
    u += 0x7FFF + ((u >> 16) & 1);          // RNE
    return (unsigned short)(u >> 16);
}
__device__ __forceinline__ float bf2f(unsigned short h) {
    unsigned u = ((unsigned)h) << 16;
    return __builtin_bit_cast(float, u);
}

// Packed-weight offsets inside Wb (bf16 elements), W3..W11 cumulative
#define O_W3 0
#define O_W4 6144
#define O_W5 18432
#define O_W6 30720
#define O_W7 55296
#define O_W8 153600
#define O_W9 546816
#define O_W10 1333248
#define O_W11 2119680

// ============================================================================
// MFMA helpers (verified across both sessions)
// ============================================================================
template<int CIN>
__device__ __forceinline__ void mfma_tile(
    const unsigned short* a0, const unsigned short* a1,
    const unsigned short* b0p, const unsigned short* b1p,
    f32x4& acc0, f32x4& acc1)
{
#pragma unroll
    for (int k = 0; k < CIN; k += 32) {
        bf16x8 A0 = __builtin_bit_cast(bf16x8, *(const float4*)(const void*)(a0 + k));
        bf16x8 A1 = __builtin_bit_cast(bf16x8, *(const float4*)(const void*)(a1 + k));
        bf16x8 B0 = __builtin_bit_cast(bf16x8, *(const float4*)(const void*)(b0p + k));
        bf16x8 B1 = __builtin_bit_cast(bf16x8, *(const float4*)(const void*)(b1p + k));
        acc0 = __builtin_amdgcn_mfma_f32_16x16x32_bf16(A0, B0, acc0, 0, 0, 0);
        acc1 = __builtin_amdgcn_mfma_f32_16x16x32_bf16(A1, B1, acc1, 0, 0, 0);
    }
}

__device__ __forceinline__ void epilogue_store(
    unsigned short* dst, const f32x4& acc0, const f32x4& acc1,
    const float* bias, int fbase, int s0, int s1)
{
    unsigned short o[4];
#pragma unroll
    for (int r = 0; r < 4; ++r) {
        float v = fmaxf(fmaxf(acc0[r] + bias[(fbase + r) * 3 + s0],
                              acc1[r] + bias[(fbase + r) * 3 + s1]), 0.f);
        o[r] = f2bf(v);
    }
    *(ushort4*)dst = make_ushort4(o[0], o[1], o[2], o[3]);
}

// ============================================================================
// HEAD (R8/R9/R10-proven streaming shape): L1+L2, no inter-wave coupling.
//   blocks 0..255  : 1024 independent waves; lane owns np2; X3 out.
//   blocks 256..511: pack W3..W11 fp32 -> bf16.
// ============================================================================
struct HeadParams {
    const float* x;
    const float* W1; const float* B1; const int* S1;
    const float* W2; const float* B2; const int* S2;
    const float* Wsrc[9];          // W3..W11 fp32
    unsigned short* Wb;
    unsigned short* X3;            // [512][128][32]
};

__global__ __launch_bounds__(256) void head_l12_pack(HeadParams P)
{
    const int tid = threadIdx.x;

    if (blockIdx.x >= 256) {
        int gt = (blockIdx.x - 256) * 256 + tid;      // 0..65535
        const int we[9] = {6144, 12288, 12288, 24576, 98304, 393216, 786432, 786432, 1572864};
        const int wo[9] = {O_W3, O_W4, O_W5, O_W6, O_W7, O_W8, O_W9, O_W10, O_W11};
#pragma unroll
        for (int li = 0; li < 9; ++li) {
            const float4* src = (const float4*)P.Wsrc[li];
            ushort4* dst = (ushort4*)(P.Wb + wo[li]);
            int n4 = we[li] >> 2;
            for (int i = gt; i < n4; i += 65536) {
                float4 w = src[i];
                dst[i] = make_ushort4(f2bf(w.x), f2bf(w.y), f2bf(w.z), f2bf(w.w));
            }
        }
        return;
    }

    __shared__ float wsm[960];
    for (int i = tid; i < 960; i += 256) {
        float v;
        if (i < 72)       v = P.W1[i];
        else if (i < 96)  v = P.B1[i - 72];
        else if (i < 864) v = P.W2[i - 96];
        else              v = P.B2[i - 864];
        wsm[i] = v;
    }
    __syncthreads();

    const float* wl1 = wsm;
    const float* bl1 = wsm + 72;
    const float* wl2 = wsm + 96;
    const float* bl2 = wsm + 864;

    const int lane = tid & 63;
    const int gw   = blockIdx.x * 4 + (tid >> 6);   // 0..1023
    const int b    = gw >> 3;                        // 0..127
    const int chunk= gw & 7;                         // 0..7
    const int np2  = chunk * 64 + lane;              // 0..511

    const float* xb = P.x + (size_t)b * 6144 + chunk * 256 + 4 * lane;
    float4 x0 = *(const float4*)(xb);
    float4 x1 = *(const float4*)(xb + 2048);
    float4 x2 = *(const float4*)(xb + 4096);
    int4 sA = *(const int4*)(P.S1 + 4 * np2);
    int2 sB = *(const int2*)(P.S2 + 2 * np2);

    float y1a[8], y1b[8];
    {
        int s0 = sA.x, s1 = sA.y;
#pragma unroll
        for (int f = 0; f < 8; ++f) {
            int r0 = f * 3 + s0, r1 = f * 3 + s1;
            float z0 = fmaf(wl1[r0*3+2], x2.x, fmaf(wl1[r0*3+1], x1.x, fmaf(wl1[r0*3+0], x0.x, bl1[r0])));
            float z1 = fmaf(wl1[r1*3+2], x2.y, fmaf(wl1[r1*3+1], x1.y, fmaf(wl1[r1*3+0], x0.y, bl1[r1])));
            y1a[f] = bf2f(f2bf(fmaxf(fmaxf(z0, z1), 0.f)));
        }
        int t0 = sA.z, t1 = sA.w;
#pragma unroll
        for (int f = 0; f < 8; ++f) {
            int r0 = f * 3 + t0, r1 = f * 3 + t1;
            float z0 = fmaf(wl1[r0*3+2], x2.z, fmaf(wl1[r0*3+1], x1.z, fmaf(wl1[r0*3+0], x0.z, bl1[r0])));
            float z1 = fmaf(wl1[r1*3+2], x2.w, fmaf(wl1[r1*3+1], x1.w, fmaf(wl1[r1*3+0], x0.w, bl1[r1])));
            y1b[f] = bf2f(f2bf(fmaxf(fmaxf(z0, z1), 0.f)));
        }
    }

    unsigned short o[32];
    {
        int s0 = sB.x, s1 = sB.y;
#pragma unroll
        for (int f = 0; f < 32; ++f) {
            const float* w0 = &wl2[(f * 3 + s0) * 8];
            const float* w1 = &wl2[(f * 3 + s1) * 8];
            float z0 = bl2[f * 3 + s0], z1 = bl2[f * 3 + s1];
#pragma unroll
            for (int k = 0; k < 8; ++k) {
                z0 = fmaf(w0[k], y1a[k], z0);
                z1 = fmaf(w1[k], y1b[k], z1);
            }
            o[f] = f2bf(fmaxf(fmaxf(z0, z1), 0.f));
        }
    }

    unsigned short* dst = P.X3 + ((size_t)np2 * 128 + b) * 32;
#pragma unroll
    for (int i2 = 0; i2 < 8; ++i2)
        *(ushort4*)(dst + 4 * i2) = make_ushort4(o[4*i2], o[4*i2+1], o[4*i2+2], o[4*i2+3]);
}

// ============================================================================
// stage2 v3: L3+L4+L5 fused. 512 blocks (n5 x 8 b-eighths) x 1024 thr
// (16 waves; 2 blocks/CU). EVERY phase is ONE round:
//   L3: 16 tasks / 16 waves; L4: 8 / waves 0..7; L5: 4 / waves 0..3.
// Mechanical re-tiling of the R10-passing body (task->wave map only).
// X3 [512][128][32] -> X6 [64][128][64]
// ============================================================================
__global__ __launch_bounds__(1024) void stage2_kernel(
    const unsigned short* __restrict__ X3,
    const unsigned short* __restrict__ Wb,   // W3@0, W4@6144, W5@18432
    const float* __restrict__ B3, const int* __restrict__ S3,
    const float* __restrict__ B4, const int* __restrict__ S4,
    const float* __restrict__ B5, const int* __restrict__ S5,
    unsigned short* __restrict__ X6)
{
    constexpr int RPE = 72;
    __shared__ unsigned short L3o[4 * 16 * RPE];   //  9216 B
    __shared__ unsigned short L4o[2 * 16 * RPE];   //  4608 B

    const int tid  = threadIdx.x;
    const int lane = tid & 63;
    const int wv   = tid >> 6;                     // 0..15
    const int c = lane & 15, q = lane >> 4;
    const int n5 = blockIdx.x >> 3;                // 0..63
    const int b0 = (blockIdx.x & 7) * 16;

    const unsigned short* W3b = Wb;
    const unsigned short* W4b = Wb + 6144;
    const unsigned short* W5b = Wb + 18432;

    // ---- L3 (cin=32, cf=64): 16 tasks, 1 round ----
    {
        int ft = wv & 3, j = wv >> 2;
        int np = 4 * n5 + j;
        int s0 = __builtin_amdgcn_readfirstlane(S3[2 * np]);
        int s1 = __builtin_amdgcn_readfirstlane(S3[2 * np + 1]);
        int f0 = ft * 16;
        const unsigned short* a0 = W3b + (size_t)((f0 + c) * 3 + s0) * 32 + q * 8;
        const unsigned short* a1 = W3b + (size_t)((f0 + c) * 3 + s1) * 32 + q * 8;
        const unsigned short* bp0 = X3 + ((size_t)(8 * n5 + 2 * j) * 128 + b0 + c) * 32 + q * 8;
        const unsigned short* bp1 = X3 + ((size_t)(8 * n5 + 2 * j + 1) * 128 + b0 + c) * 32 + q * 8;
        f32x4 acc0 = {0.f,0.f,0.f,0.f}, acc1 = {0.f,0.f,0.f,0.f};
        mfma_tile<32>(a0, a1, bp0, bp1, acc0, acc1);
        epilogue_store(&L3o[((size_t)j * 16 + c) * RPE + f0 + q * 4],
                       acc0, acc1, B3, f0 + q * 4, s0, s1);
    }
    __syncthreads();

    // ---- L4 (cin=64, cf=64): 8 tasks, 1 round (waves 0..7) ----
    if (wv < 8) {
        int ft = wv & 3, j = wv >> 2;
        int np = 2 * n5 + j;
        int s0 = __builtin_amdgcn_readfirstlane(S4[2 * np]);
        int s1 = __builtin_amdgcn_readfirstlane(S4[2 * np + 1]);
        int f0 = ft * 16;
        const unsigned short* a0 = W4b + (size_t)((f0 + c) * 3 + s0) * 64 + q * 8;
        const unsigned short* a1 = W4b + (size_t)((f0 + c) * 3 + s1) * 64 + q * 8;
        const unsigned short* bp0 = &L3o[((size_t)(2 * j) * 16 + c) * RPE + q * 8];
        const unsigned short* bp1 = &L3o[((size_t)(2 * j + 1) * 16 + c) * RPE + q * 8];
        f32x4 acc0 = {0.f,0.f,0.f,0.f}, acc1 = {0.f,0.f,0.f,0.f};
        mfma_tile<64>(a0, a1, bp0, bp1, acc0, acc1);
        epilogue_store(&L4o[((size_t)j * 16 + c) * RPE + f0 + q * 4],
                       acc0, acc1, B4, f0 + q * 4, s0, s1);
    }
    __syncthreads();

    // ---- L5 (cin=64, cf=64): 4 tasks, 1 round (waves 0..3) ----
    if (wv < 4) {
        int ft = wv;
        int s0 = __builtin_amdgcn_readfirstlane(S5[2 * n5]);
        int s1 = __builtin_amdgcn_readfirstlane(S5[2 * n5 + 1]);
        int f0 = ft * 16;
        const unsigned short* a0 = W5b + (size_t)((f0 + c) * 3 + s0) * 64 + q * 8;
        const unsigned short* a1 = W5b + (size_t)((f0 + c) * 3 + s1) * 64 + q * 8;
        const unsigned short* bp0 = &L4o[((size_t)(0) * 16 + c) * RPE + q * 8];
        const unsigned short* bp1 = &L4o[((size_t)(1) * 16 + c) * RPE + q * 8];
        f32x4 acc0 = {0.f,0.f,0.f,0.f}, acc1 = {0.f,0.f,0.f,0.f};
        mfma_tile<64>(a0, a1, bp0, bp1, acc0, acc1);
        epilogue_store(X6 + ((size_t)n5 * 128 + b0 + c) * 64 + f0 + q * 4,
                       acc0, acc1, B5, f0 + q * 4, s0, s1);
    }
}

// ============================================================================
// stage67 v2: L6+L7 fused. 128 blocks x 1024 thr (16 waves).
// EVERY phase is ONE round: L6 16 tasks / 16 waves; L7 16 / 16.
// Mechanical re-tiling of the R10-passing body.
// X6 [64][128][64] -> X8 [16][128][256]
// ============================================================================
__global__ __launch_bounds__(1024) void stage67_kernel(
    const unsigned short* __restrict__ X6,
    const unsigned short* __restrict__ W6b, const float* __restrict__ B6, const int* __restrict__ S6,
    const unsigned short* __restrict__ W7b, const float* __restrict__ B7, const int* __restrict__ S7,
    unsigned short* __restrict__ X8)
{
    constexpr int RPE = 136;                       // 128 + 8 pad
    __shared__ unsigned short L6o[2 * 16 * RPE];   // 8.7 KB

    const int tid  = threadIdx.x;
    const int lane = tid & 63;
    const int wv   = tid >> 6;                     // 0..15
    const int c = lane & 15, q = lane >> 4;
    const int n7 = blockIdx.x >> 3;                // 0..15
    const int b0 = (blockIdx.x & 7) * 16;

    // ---- L6 (CIN=64, CF=128): 16 tasks, 1 round ----
    {
        int j = wv >> 3, ft = wv & 7;
        int np = 2 * n7 + j;
        int s0 = __builtin_amdgcn_readfirstlane(S6[2 * np]);
        int s1 = __builtin_amdgcn_readfirstlane(S6[2 * np + 1]);
        int f0 = ft * 16;
        const unsigned short* a0 = W6b + (size_t)((f0 + c) * 3 + s0) * 64 + q * 8;
        const unsigned short* a1 = W6b + (size_t)((f0 + c) * 3 + s1) * 64 + q * 8;
        const unsigned short* bp0 = X6 + ((size_t)(2 * np) * 128 + b0 + c) * 64 + q * 8;
        const unsigned short* bp1 = X6 + ((size_t)(2 * np + 1) * 128 + b0 + c) * 64 + q * 8;
        f32x4 acc0 = {0.f,0.f,0.f,0.f}, acc1 = {0.f,0.f,0.f,0.f};
        mfma_tile<64>(a0, a1, bp0, bp1, acc0, acc1);
        epilogue_store(&L6o[((size_t)j * 16 + c) * RPE + f0 + q * 4],
                       acc0, acc1, B6, f0 + q * 4, s0, s1);
    }
    __syncthreads();

    // ---- L7 (CIN=128, CF=256): 16 tasks, 1 round ----
    {
        int s0 = __builtin_amdgcn_readfirstlane(S7[2 * n7]);
        int s1 = __builtin_amdgcn_readfirstlane(S7[2 * n7 + 1]);
        int f0 = wv * 16;
        const unsigned short* a0 = W7b + (size_t)((f0 + c) * 3 + s0) * 128 + q * 8;
        const unsigned short* a1 = W7b + (size_t)((f0 + c) * 3 + s1) * 128 + q * 8;
        const unsigned short* bp0 = &L6o[((size_t)(0) * 16 + c) * RPE + q * 8];
        const unsigned short* bp1 = &L6o[((size_t)(1) * 16 + c) * RPE + q * 8];
        f32x4 acc0 = {0.f,0.f,0.f,0.f}, acc1 = {0.f,0.f,0.f,0.f};
        mfma_tile<128>(a0, a1, bp0, bp1, acc0, acc1);
        epilogue_store(X8 + ((size_t)n7 * 128 + b0 + c) * 256 + f0 + q * 4,
                       acc0, acc1, B7, f0 + q * 4, s0, s1);
    }
}

// ============================================================================
// Flat MFMA layer (L8..L11): verified body (verbatim).
// ============================================================================
template<int CIN, int CF, int NP, int MW, int NW>
__global__ __launch_bounds__(256) void mfma_kernel(
    const unsigned short* __restrict__ Xin,
    const unsigned short* __restrict__ Wb,
    const float* __restrict__ bias,
    const int*   __restrict__ sel,
    unsigned short* __restrict__ Xout)
{
    constexpr int FT = CF / (16 * MW);
    constexpr int BT = 128 / (16 * NW);

    const int wid  = threadIdx.x >> 6;
    const int lane = threadIdx.x & 63;
    const int task = blockIdx.x * 4 + wid;
    const int bi = task % BT;
    const int fi = (task / BT) % FT;
    const int n  = task / (BT * FT);

    const int c = lane & 15;
    const int q = lane >> 4;
    const int s0 = __builtin_amdgcn_readfirstlane(sel[2 * n]);
    const int s1 = __builtin_amdgcn_readfirstlane(sel[2 * n + 1]);

    const int f0 = fi * 16 * MW;
    const int b0 = bi * 16 * NW;

    const unsigned short* ap[2][MW];
    const unsigned short* bp[2][NW];
#pragma unroll
    for (int p = 0; p < 2; ++p) {
        int s = p ? s1 : s0;
#pragma unroll
        for (int mi = 0; mi < MW; ++mi)
            ap[p][mi] = Wb + (size_t)((f0 + mi * 16 + c) * 3 + s) * CIN + q * 8;
#pragma unroll
        for (int ni = 0; ni < NW; ++ni)
            bp[p][ni] = Xin + ((size_t)(2 * n + p) * 128 + b0 + ni * 16 + c) * CIN + q * 8;
    }

    f32x4 acc[2][MW][NW];
#pragma unroll
    for (int p = 0; p < 2; ++p)
#pragma unroll
        for (int mi = 0; mi < MW; ++mi)
#pragma unroll
            for (int ni = 0; ni < NW; ++ni)
                acc[p][mi][ni] = (f32x4){0.f, 0.f, 0.f, 0.f};

#pragma unroll 2
    for (int k = 0; k < CIN; k += 32) {
        bf16x8 A[2][MW], B[2][NW];
#pragma unroll
        for (int p = 0; p < 2; ++p) {
#pragma unroll
            for (int mi = 0; mi < MW; ++mi)
                A[p][mi] = __builtin_bit_cast(bf16x8, *(const float4*)(const void*)(ap[p][mi] + k));
#pragma unroll
            for (int ni = 0; ni < NW; ++ni)
                B[p][ni] = __builtin_bit_cast(bf16x8, *(const float4*)(const void*)(bp[p][ni] + k));
        }
#pragma unroll
        for (int p = 0; p < 2; ++p)
#pragma unroll
            for (int mi = 0; mi < MW; ++mi)
#pragma unroll
                for (int ni = 0; ni < NW; ++ni)
                    acc[p][mi][ni] = __builtin_amdgcn_mfma_f32_16x16x32_bf16(
                        A[p][mi], B[p][ni], acc[p][mi][ni], 0, 0, 0);
    }

#pragma unroll
    for (int mi = 0; mi < MW; ++mi) {
        int fbase = f0 + mi * 16 + q * 4;
#pragma unroll
        for (int ni = 0; ni < NW; ++ni) {
            int b = b0 + ni * 16 + c;
            epilogue_store(Xout + ((size_t)n * 128 + b) * CF + fbase,
                           acc[0][mi][ni], acc[1][mi][ni], bias, fbase, s0, s1);
        }
    }
}

// ============================================================================
// FC head: h bf16 [128][1024]; out [128][16] fp32 log-softmax (verbatim)
// ============================================================================
__global__ __launch_bounds__(256) void fc_logsoftmax_kernel(
    const unsigned short* __restrict__ h, const float* __restrict__ fcW,
    const float* __restrict__ fcb, float* __restrict__ out)
{
    int b   = blockIdx.x;
    int tid = threadIdx.x;
    int k     = tid & 15;
    int chunk = tid >> 4;

    const float* __restrict__ wk = fcW + (size_t)k * 1024;
    const unsigned short* hb = h + (size_t)b * 1024;

    float partial = 0.0f;
    int j0 = chunk * 64;
#pragma unroll 8
    for (int j = 0; j < 64; ++j)
        partial = fmaf(bf2f(hb[j0 + j]), wk[j0 + j], partial);

    __shared__ float red[16][17];
    red[chunk][k] = partial;
    __syncthreads();

    __shared__ float logits[16];
    if (tid < 16) {
        float s = fcb[tid];
#pragma unroll
        for (int c = 0; c < 16; ++c) s += red[c][tid];
        logits[tid] = s;
    }
    __syncthreads();

    if (tid < 16) {
        float mx = -INFINITY;
#pragma unroll
        for (int kk = 0; kk < 16; ++kk) mx = fmaxf(mx, logits[kk]);
        float se = 0.0f;
#pragma unroll
        for (int kk = 0; kk < 16; ++kk) se += expf(logits[kk] - mx);
        out[b * 16 + tid] = logits[tid] - mx - logf(se);
    }
}

// ============================================================================
extern "C" void kernel_launch(void* const* d_in, const int* in_sizes, int n_in,
                              void* d_out, int out_size, void* d_ws, size_t ws_size,
                              hipStream_t stream)
{
#define WL(i) (const float*)d_in[1 + 3 * (i)]
#define BL(i) (const float*)d_in[2 + 3 * (i)]
#define SL(i) (const int*)  d_in[3 + 3 * (i)]

    unsigned short* bufA = (unsigned short*)d_ws;          // 4 MB
    unsigned short* bufB = bufA + 2u * 1024u * 1024u;      // 4 MB
    unsigned short* X3   = bufB + 2u * 1024u * 1024u;      // 4 MB [512][128][32]
    unsigned short* Wb   = X3   + 2u * 1024u * 1024u;      // packed bf16 W3..W11

    // ---- K1: streaming L1+L2 -> X3  ||  pack W3..W11 -> Wb ----
    HeadParams HP;
    HP.x  = (const float*)d_in[0];
    HP.W1 = WL(0); HP.B1 = BL(0); HP.S1 = SL(0);
    HP.W2 = WL(1); HP.B2 = BL(1); HP.S2 = SL(1);
    for (int i = 0; i < 9; ++i) HP.Wsrc[i] = WL(2 + i);
    HP.Wb = Wb; HP.X3 = X3;
    head_l12_pack<<<512, 256, 0, stream>>>(HP);

    // ---- K2: L3+L4+L5 -> X6 (bufB)  [v3: 512 blocks x 1024 thr, 3 rounds] ----
    stage2_kernel<<<512, 1024, 0, stream>>>(X3, Wb,
        BL(2), SL(2), BL(3), SL(3), BL(4), SL(4), bufB);

    // ---- K3: L6+L7 -> X8 (bufA)  [v2: 128 blocks x 1024 thr, 2 rounds] ----
    stage67_kernel<<<128, 1024, 0, stream>>>(bufB,
        Wb + O_W6, BL(5), SL(5), Wb + O_W7, BL(6), SL(6), bufA);

    // ---- K4..K7: flat MFMA layers L8..L11 ----
    mfma_kernel<256, 512, 8, 2, 2><<<128, 256, 0, stream>>>(bufA, Wb + O_W8,  BL(7),  SL(7),  bufB);
    mfma_kernel<512, 512, 4, 1, 1><<<256, 256, 0, stream>>>(bufB, Wb + O_W9,  BL(8),  SL(8),  bufA);
    mfma_kernel<512, 512, 2, 1, 1><<<128, 256, 0, stream>>>(bufA, Wb + O_W10, BL(9),  SL(9),  bufB);
    mfma_kernel<512, 1024, 1, 1, 1><<<128, 256, 0, stream>>>(bufB, Wb + O_W11, BL(10), SL(10), bufA);

    // ---- K8: FC ----
    fc_logsoftmax_kernel<<<128, 256, 0, stream>>>(bufA, (const float*)d_in[34], (const float*)d_in[35], (float*)d_out);

#undef WL
#undef BL
#undef SL
}